// Round 3
// baseline (691.377 us; speedup 1.0000x reference)
//
#include <hip/hip_runtime.h>
#include <hip/hip_cooperative_groups.h>

namespace cg = cooperative_groups;

// Single cooperative kernel: 199 steps = 13 supersteps of <=16 LDS-fused steps.
// Cross-superstep halo exchange via global slices + grid.sync() (device-scope
// fence INSIDE one kernel node -> no reliance on graph-node-boundary coherence,
// which is the prime suspect for round 2's post-timing divergence).
//
// Block: 1024 threads, one 64x64 region (32x32 owned tile + 16-halo).
// Thread (r = tid>>4, qc = tid&15) owns the 4-col quad (r, 4qc..4qc+3).
// Center row cached in registers across steps: own written value o4 equals
// cur[lrc][c0..3] for ALL threads (interior: lrc==r; row-clamped threads
// compute from identical row triples -> identical values; verified case by
// case for top/bottom domain edges and region-edge garbage rows).
//
// Physics per step (validated by round-1 pass):
//   final(i,j) = inner(clamp(i,1,510), clamp(j,1,510))
//   inner(ic,jc): jc==255 -> (k1*T[ic,jc+1]+k2*T[ic,jc-1])/(k1+k2)   (old T)
//                 else    -> Tc - DT*kap*(Tc^2*Tx - Tc*Ty)
//                            + DT*alp*(Txx+Tyy) + DT*kap*(Tc^3-Tc^2+Tc)
// Row mirror: clamped LDS row addresses (lrm/lrc/lrp).
// Col mirror: final(i,0)==final(i,1), final(i,511)==final(i,510) -> fixL/fixR
// in-quad copies. Interface col gj==255 handled wherever it appears (owned or
// halo). Region-edge garbage propagates 1 cell/step; owned tile is 16 deep.

#define GN 512
#define GNN (GN * GN)
#define NSTEPS 199
#define TS 32
#define KMAX 16
#define W 64

constexpr float kCdiff = (float)(1e-7 * 511.0 * 511.0); // DT/dx^2
constexpr float kCadv  = (float)(1e-7 * 511.0 / 2.0);   // DT/(2 dx)
constexpr float kCrea  = 1e-7f;                         // DT

__global__ __launch_bounds__(1024) void adr_coop(
    const float* __restrict__ u0, float* __restrict__ out,
    const float* __restrict__ pk1, const float* __restrict__ pk2,
    const float* __restrict__ pa1, const float* __restrict__ pa2)
{
    __shared__ float bufA[W * W];
    __shared__ float bufB[W * W];

    const int tid = threadIdx.x;   // 0..1023
    const int qc  = tid & 15;      // col quad
    const int r   = tid >> 4;      // local row 0..63
    const int c0  = qc * 4;
    const int bi0 = ((int)blockIdx.x >> 4) * TS;
    const int bj0 = ((int)blockIdx.x & 15) * TS;

    const float k1 = pk1[0], k2 = pk2[0], a1 = pa1[0], a2 = pa2[0];
    const float inv_k12 = 1.0f / (k1 + k2);

    // ---- column constants ----
    float kap[4], alp[4];
    bool  iface[4];
#pragma unroll
    for (int t = 0; t < 4; ++t) {
        const int gj = bj0 - KMAX + c0 + t;
        const int jc = min(max(gj, 1), GN - 2);
        kap[t]   = (jc < 256) ? k1 : k2;
        alp[t]   = (jc < 256) ? a1 : a2;
        iface[t] = (gj == 255);
    }
    const bool fixL = (bj0 == 0)       && (qc == 4);   // gj==0  at t=0
    const bool fixR = (bj0 == GN - TS) && (qc == 11);  // gj==511 at t=3
    const int lsCol = max(c0 - 1, 0);
    const int rsCol = min(c0 + 4, W - 1);
    const bool ownedW = (qc >= 4) && (qc < 12) && (r >= KMAX) && (r < KMAX + TS);

    // ---- row constants ----
    const int gi  = bi0 - KMAX + r;
    const int ic  = min(max(gi, 1), GN - 2);
    const int lrm = min(max(ic - 1 - (bi0 - KMAX), 0), W - 1);
    const int lrc = min(max(ic     - (bi0 - KMAX), 0), W - 1);
    const int lrp = min(max(ic + 1 - (bi0 - KMAX), 0), W - 1);
    const int gci = min(max(gi, 0), GN - 1);           // initial-load row
    const int gw  = (bi0 + r - KMAX) * GN + (bj0 + c0 - KMAX); // owned write off

    cg::grid_group grid = cg::this_grid();

    for (int done = 0; done < NSTEPS; done += KMAX) {
        const int k = min(KMAX, NSTEPS - done);
        const float* src = done ? (out + (size_t)(done - 1) * GNN) : u0;

        // ---- load region (clamped) into bufA ----
        {
            float4 v;
            const float* srow = src + gci * GN;
            const int gj0 = bj0 - KMAX + c0;
            v.x = srow[min(max(gj0 + 0, 0), GN - 1)];
            v.y = srow[min(max(gj0 + 1, 0), GN - 1)];
            v.z = srow[min(max(gj0 + 2, 0), GN - 1)];
            v.w = srow[min(max(gj0 + 3, 0), GN - 1)];
            *(float4*)&bufA[r * W + c0] = v;
        }
        float* cur = bufA;
        float* nxt = bufB;
        __syncthreads();

        float4 cc = *(const float4*)&cur[lrc * W + c0];

        for (int s = 0; s < k; ++s) {
            float* slice = out + (size_t)(done + s) * GNN;

            const float4 up = *(const float4*)&cur[lrm * W + c0];
            const float4 dn = *(const float4*)&cur[lrp * W + c0];
            const float  ls = cur[lrc * W + lsCol];
            const float  rs = cur[lrc * W + rsCol];

            const float ccv[4] = {cc.x, cc.y, cc.z, cc.w};
            const float upv[4] = {up.x, up.y, up.z, up.w};
            const float dnv[4] = {dn.x, dn.y, dn.z, dn.w};
            const float tlv[4] = {ls,   cc.x, cc.y, cc.z};
            const float trv[4] = {cc.y, cc.z, cc.w, rs  };

            float o[4];
#pragma unroll
            for (int t = 0; t < 4; ++t) {
                const float tc = ccv[t], tm = upv[t], tp = dnv[t];
                const float tl = tlv[t], tr = trv[t];
                const float t2  = tc * tc;
                const float adv = kap[t] * kCadv * (t2 * (tp - tm) - tc * (tr - tl));
                const float dif = alp[t] * kCdiff * ((tm + tp + tl + tr) - 4.0f * tc);
                const float rea = kCrea * kap[t] * ((t2 * tc - t2) + tc);
                const float v   = tc - adv + dif + rea;
                const float vi  = (k1 * tr + k2 * tl) * inv_k12;
                o[t] = iface[t] ? vi : v;
            }
            if (fixL) o[0] = o[1];
            if (fixR) o[3] = o[2];

            const float4 o4 = make_float4(o[0], o[1], o[2], o[3]);
            *(float4*)&nxt[r * W + c0] = o4;
            if (ownedW) *(float4*)&slice[gw] = o4;

            __syncthreads();
            float* tswap = cur; cur = nxt; nxt = tswap;
            cc = o4;   // == cur[lrc][c0..3] by the row-value-coincidence argument
        }

        grid.sync();   // device-scope fence + barrier: slice done+k-1 visible
    }
}

extern "C" void kernel_launch(void* const* d_in, const int* in_sizes, int n_in,
                              void* d_out, int out_size, void* d_ws, size_t ws_size,
                              hipStream_t stream) {
    (void)in_sizes; (void)n_in; (void)out_size; (void)d_ws; (void)ws_size;

    const float* u0 = (const float*)d_in[0];
    const float* k1 = (const float*)d_in[1];
    const float* k2 = (const float*)d_in[2];
    const float* a1 = (const float*)d_in[3];
    const float* a2 = (const float*)d_in[4];
    float* out = (float*)d_out;

    void* args[] = {(void*)&u0, (void*)&out,
                    (void*)&k1, (void*)&k2, (void*)&a1, (void*)&a2};
    hipLaunchCooperativeKernel((const void*)adr_coop, dim3(256), dim3(1024),
                               args, 0, stream);
}